// Round 7
// baseline (36.986 us; speedup 1.0000x reference)
//
#include <hip/hip_runtime.h>

// One thread per batch (3x3 complex). 256 batches/block, 4 waves, wave-private
// LDS, zero __syncthreads(). Single 1152-f32 buffer/wave (4608 B) reused
// V -> U0 -> out. Staging uses __builtin_amdgcn_global_load_lds (direct DMA,
// zero register residency -> no spill pressure, R5/R6 lesson). U0's DMA is
// issued right after phase-1's V ds_reads complete and overlaps the ~220-instr
// E computation. Explicit in-wave waitcnt fences order DMA/ds_read/reuse.
// LDS 18432 B/block; __launch_bounds__(256,6) -> target 24 waves/CU.

#define BPB 256

typedef const __attribute__((address_space(1))) void gvoid_t;
typedef __attribute__((address_space(3))) void lvoid_t;

__device__ __forceinline__ void g2l16(const void* g, void* l) {
    // 16B per lane: LDS dest = (uniform) l + lane*16, src = per-lane g
    __builtin_amdgcn_global_load_lds((gvoid_t*)g, (lvoid_t*)l, 16, 0, 0);
}

__global__ __launch_bounds__(256, 6)
void sun_diffuse_kernel(const float* __restrict__ U0_re, const float* __restrict__ U0_im,
                        const float* __restrict__ xs,
                        const float* __restrict__ V_re, const float* __restrict__ V_im,
                        float* __restrict__ out, int nb)
{
    __shared__ __align__(16) float smem[4][1152];   // per-wave: 64 batches

    const int tid  = threadIdx.x;
    const int w    = tid >> 6;
    const int lane = tid & 63;
    const int wb0  = blockIdx.x * BPB + w * 64;
    const int nw   = min(max(nb - wb0, 0), 64);

    float*  S  = smem[w];
    float4* S4 = reinterpret_cast<float4*>(S);      // 288 float4

    if (nw == 64) {
        // ---- issue V -> LDS DMA (144 float4 per plane; wb0*36 B is 16B-aligned) ----
        const float4* gVr = reinterpret_cast<const float4*>(V_re + (size_t)wb0 * 9);
        const float4* gVi = reinterpret_cast<const float4*>(V_im + (size_t)wb0 * 9);
        g2l16(gVr + lane,       S4);
        g2l16(gVr + 64 + lane,  S4 + 64);
        if (lane < 16) g2l16(gVr + 128 + lane, S4 + 128);
        g2l16(gVi + lane,       S4 + 144);
        g2l16(gVi + 64 + lane,  S4 + 208);
        if (lane < 16) g2l16(gVi + 128 + lane, S4 + 272);

        // ---- xs per-lane direct (overlaps V DMA) ----
        const size_t xb = (size_t)(wb0 + lane) * 3;
        float pr[3], pi[3];
#pragma unroll
        for (int k = 0; k < 3; ++k) {
            float s, c;
            __sincosf(xs[xb + k], &s, &c);
            pr[k] = c; pi[k] = s;
        }

        // ---- wait V DMA landed, read V fragments ----
        asm volatile("s_waitcnt vmcnt(0)" ::: "memory");
        float vr[9], vi[9];
#pragma unroll
        for (int m = 0; m < 9; ++m) {
            vr[m] = S[lane * 9 + m];
            vi[m] = S[576 + lane * 9 + m];
        }
        // all V reads drained -> buffer reusable
        asm volatile("s_waitcnt lgkmcnt(0)" ::: "memory");

        // ---- issue U0 -> same LDS buffer (overlaps E computation below) ----
        const float4* gUr = reinterpret_cast<const float4*>(U0_re + (size_t)wb0 * 9);
        const float4* gUi = reinterpret_cast<const float4*>(U0_im + (size_t)wb0 * 9);
        g2l16(gUr + lane,       S4);
        g2l16(gUr + 64 + lane,  S4 + 64);
        if (lane < 16) g2l16(gUr + 128 + lane, S4 + 128);
        g2l16(gUi + lane,       S4 + 144);
        g2l16(gUi + 64 + lane,  S4 + 208);
        if (lane < 16) g2l16(gUi + 128 + lane, S4 + 272);

        // ---- phase 1: E = V diag(e^{ix}) V^H (~220 VALU, hides U0 DMA) ----
        float Er[9], Ei[9];
#pragma unroll
        for (int i = 0; i < 3; ++i) {
#pragma unroll
            for (int j = 0; j < 3; ++j) {
                float er = 0.f, ei = 0.f;
#pragma unroll
                for (int k = 0; k < 3; ++k) {
                    float wr = pr[k] * vr[i * 3 + k] - pi[k] * vi[i * 3 + k];
                    float wi = pr[k] * vi[i * 3 + k] + pi[k] * vr[i * 3 + k];
                    er += wr * vr[j * 3 + k] + wi * vi[j * 3 + k];
                    ei += wi * vr[j * 3 + k] - wr * vi[j * 3 + k];
                }
                Er[i * 3 + j] = er; Ei[i * 3 + j] = ei;
            }
        }

        // ---- wait U0 DMA, read U0, compute Ut = E @ U0 ----
        asm volatile("s_waitcnt vmcnt(0)" ::: "memory");
        float ur[9], ui[9];
#pragma unroll
        for (int m = 0; m < 9; ++m) {
            ur[m] = S[lane * 9 + m];
            ui[m] = S[576 + lane * 9 + m];
        }
        // U0 reads drained -> buffer reusable for output
        asm volatile("s_waitcnt lgkmcnt(0)" ::: "memory");

        float2* S2 = reinterpret_cast<float2*>(S);  // interleaved re/im, 8B stores
#pragma unroll
        for (int i = 0; i < 3; ++i) {
#pragma unroll
            for (int j = 0; j < 3; ++j) {
                float r = 0.f, im = 0.f;
#pragma unroll
                for (int k = 0; k < 3; ++k) {
                    r  += Er[i * 3 + k] * ur[k * 3 + j] - Ei[i * 3 + k] * ui[k * 3 + j];
                    im += Er[i * 3 + k] * ui[k * 3 + j] + Ei[i * 3 + k] * ur[k * 3 + j];
                }
                S2[lane * 9 + i * 3 + j] = make_float2(r, im);
            }
        }

        // ---- coalesced flush: 288 float4 (in-wave DS order: reads after writes) ----
        float4* gO = reinterpret_cast<float4*>(out + (size_t)wb0 * 18);
#pragma unroll
        for (int r = 0; r < 5; ++r) {
            const int i = lane + r * 64;            // 288 = 4*64 + 32
            if (i < 288) gO[i] = S4[i];
        }
    } else if (lane < nw) {
        // ---- tail (never hit at B=524288): simple direct path ----
        const size_t mb = (size_t)(wb0 + lane) * 9;
        const size_t xb = (size_t)(wb0 + lane) * 3;
        float vr[9], vi[9], ur[9], ui[9];
#pragma unroll
        for (int m = 0; m < 9; ++m) {
            vr[m] = V_re[mb + m];  vi[m] = V_im[mb + m];
            ur[m] = U0_re[mb + m]; ui[m] = U0_im[mb + m];
        }
        float pr[3], pi[3];
#pragma unroll
        for (int k = 0; k < 3; ++k) { float s, c; __sincosf(xs[xb + k], &s, &c); pr[k] = c; pi[k] = s; }
        float Er[9], Ei[9];
#pragma unroll
        for (int i = 0; i < 3; ++i)
#pragma unroll
            for (int j = 0; j < 3; ++j) {
                float er = 0.f, ei = 0.f;
#pragma unroll
                for (int k = 0; k < 3; ++k) {
                    float wr = pr[k] * vr[i * 3 + k] - pi[k] * vi[i * 3 + k];
                    float wi = pr[k] * vi[i * 3 + k] + pi[k] * vr[i * 3 + k];
                    er += wr * vr[j * 3 + k] + wi * vi[j * 3 + k];
                    ei += wi * vr[j * 3 + k] - wr * vi[j * 3 + k];
                }
                Er[i * 3 + j] = er; Ei[i * 3 + j] = ei;
            }
#pragma unroll
        for (int i = 0; i < 3; ++i)
#pragma unroll
            for (int j = 0; j < 3; ++j) {
                float r = 0.f, im = 0.f;
#pragma unroll
                for (int k = 0; k < 3; ++k) {
                    r  += Er[i * 3 + k] * ur[k * 3 + j] - Ei[i * 3 + k] * ui[k * 3 + j];
                    im += Er[i * 3 + k] * ui[k * 3 + j] + Ei[i * 3 + k] * ur[k * 3 + j];
                }
                out[((size_t)(wb0 + lane) * 9 + i * 3 + j) * 2]     = r;
                out[((size_t)(wb0 + lane) * 9 + i * 3 + j) * 2 + 1] = im;
            }
    }
}

extern "C" void kernel_launch(void* const* d_in, const int* in_sizes, int n_in,
                              void* d_out, int out_size, void* d_ws, size_t ws_size,
                              hipStream_t stream) {
    const float* U0_re = (const float*)d_in[0];
    const float* U0_im = (const float*)d_in[1];
    const float* xs    = (const float*)d_in[2];
    const float* V_re  = (const float*)d_in[3];
    const float* V_im  = (const float*)d_in[4];
    float* out = (float*)d_out;

    const int nb = in_sizes[2] / 3;
    const int grid = (nb + BPB - 1) / BPB;
    sun_diffuse_kernel<<<grid, 256, 0, stream>>>(U0_re, U0_im, xs, V_re, V_im, out, nb);
}

// Round 8
// 26.042 us; speedup vs baseline: 1.4202x; 1.4202x over previous
//
#include <hip/hip_runtime.h>

// R2 champion structure (single-burst staged loads, wave-private LDS, zero
// __syncthreads) + two micro-opts:
//  - __sincosf -> raw v_sin_f32/v_cos_f32 builtins (input in revolutions:
//    x * 1/2pi). No pointer outs -> no libcall/scratch possible.
//  - xs read per-lane directly (tiny; 6 lines/instr via L1), LDS slice
//    shrinks 9984 -> 9216 B/wave (36864 B/block).
// One burst: all 12 float4 staged loads issue before any dependent wait ->
// single HBM latency exposure per wave; 16 waves/CU x 12 KiB in flight.

#define BPB 256
#define INV2PI 0.15915494309189535f

__global__ __launch_bounds__(256, 4)
void sun_diffuse_kernel(const float* __restrict__ U0_re, const float* __restrict__ U0_im,
                        const float* __restrict__ xs,
                        const float* __restrict__ V_re, const float* __restrict__ V_im,
                        float* __restrict__ out, int nb)
{
    // per-wave slice: Vre[576] Vim[576] U0re[576] U0im[576] = 2304 f32 (9216 B)
    __shared__ __align__(16) float smem[4][2304];

    const int tid  = threadIdx.x;
    const int w    = tid >> 6;
    const int lane = tid & 63;
    const int wb0  = blockIdx.x * BPB + w * 64;        // first batch of this wave
    const int nw   = min(max(nb - wb0, 0), 64);        // batches this wave owns
    const bool full = (nw == 64);

    float* S     = smem[w];
    float* sVre  = S;
    float* sVim  = S + 576;
    float* sU0re = S + 1152;
    float* sU0im = S + 1728;

    if (full) {
        // one burst: 12 coalesced float4 loads (144 per array; wb0*36 B 16B-aligned)
        const float4* g0 = reinterpret_cast<const float4*>(V_re  + (size_t)wb0 * 9);
        const float4* g1 = reinterpret_cast<const float4*>(V_im  + (size_t)wb0 * 9);
        const float4* g2 = reinterpret_cast<const float4*>(U0_re + (size_t)wb0 * 9);
        const float4* g3 = reinterpret_cast<const float4*>(U0_im + (size_t)wb0 * 9);
        float4* s0 = reinterpret_cast<float4*>(sVre);
        float4* s1 = reinterpret_cast<float4*>(sVim);
        float4* s2 = reinterpret_cast<float4*>(sU0re);
        float4* s3 = reinterpret_cast<float4*>(sU0im);
#pragma unroll
        for (int r = 0; r < 3; ++r) {
            const int i = lane + r * 64;               // 144 = 2*64 + 16
            if (i < 144) { s0[i] = g0[i]; s1[i] = g1[i]; s2[i] = g2[i]; s3[i] = g3[i]; }
        }
    } else {
        for (int i = lane; i < nw * 9; i += 64) {
            sVre[i]  = V_re [(size_t)wb0 * 9 + i];
            sVim[i]  = V_im [(size_t)wb0 * 9 + i];
            sU0re[i] = U0_re[(size_t)wb0 * 9 + i];
            sU0im[i] = U0_im[(size_t)wb0 * 9 + i];
        }
    }
    // no barrier: wave-private data; compiler waitcnts order vmem->lds->valu

    float outr[9], outi[9];
    if (lane < nw) {
        // phases: direct per-lane xs (3 dwords), raw HW sin/cos (revolutions)
        const size_t xb = (size_t)(wb0 + lane) * 3;
        float pr[3], pi[3];
#pragma unroll
        for (int k = 0; k < 3; ++k) {
            const float rv = xs[xb + k] * INV2PI;
            pr[k] = __builtin_amdgcn_cosf(rv);
            pi[k] = __builtin_amdgcn_sinf(rv);
        }

        float vr[9], vi[9], ur[9], ui[9];
#pragma unroll
        for (int m = 0; m < 9; ++m) {
            vr[m] = sVre [lane * 9 + m];
            vi[m] = sVim [lane * 9 + m];
            ur[m] = sU0re[lane * 9 + m];
            ui[m] = sU0im[lane * 9 + m];
        }

        // E_ij = sum_k p_k * V_ik * conj(V_jk)
        float Er[9], Ei[9];
#pragma unroll
        for (int i = 0; i < 3; ++i) {
#pragma unroll
            for (int j = 0; j < 3; ++j) {
                float er = 0.f, ei = 0.f;
#pragma unroll
                for (int k = 0; k < 3; ++k) {
                    float wr = pr[k] * vr[i * 3 + k] - pi[k] * vi[i * 3 + k];
                    float wi = pr[k] * vi[i * 3 + k] + pi[k] * vr[i * 3 + k];
                    er += wr * vr[j * 3 + k] + wi * vi[j * 3 + k];
                    ei += wi * vr[j * 3 + k] - wr * vi[j * 3 + k];
                }
                Er[i * 3 + j] = er; Ei[i * 3 + j] = ei;
            }
        }
        // Ut = E @ U0
#pragma unroll
        for (int i = 0; i < 3; ++i) {
#pragma unroll
            for (int j = 0; j < 3; ++j) {
                float r = 0.f, im = 0.f;
#pragma unroll
                for (int k = 0; k < 3; ++k) {
                    r  += Er[i * 3 + k] * ur[k * 3 + j] - Ei[i * 3 + k] * ui[k * 3 + j];
                    im += Er[i * 3 + k] * ui[k * 3 + j] + Ei[i * 3 + k] * ur[k * 3 + j];
                }
                outr[i * 3 + j] = r; outi[i * 3 + j] = im;
            }
        }
    }

    // stage output (18 f32/batch, re/im interleaved) into reused slice head
    // (in-wave DS ordering: these writes can't pass the fragment reads above)
    float2* S2 = reinterpret_cast<float2*>(S);
    if (lane < nw) {
#pragma unroll
        for (int m = 0; m < 9; ++m)
            S2[lane * 9 + m] = make_float2(outr[m], outi[m]);
    }

    if (full) {
        // 64*18 = 1152 f32 = 288 float4; byte base wb0*72 is 16B-aligned
        float4* gO = reinterpret_cast<float4*>(out + (size_t)wb0 * 18);
        const float4* s = reinterpret_cast<const float4*>(S);
#pragma unroll
        for (int r = 0; r < 5; ++r) {
            const int i = lane + r * 64;               // 288 = 4*64 + 32
            if (i < 288) gO[i] = s[i];
        }
    } else if (nw > 0) {
        for (int i = lane; i < nw * 18; i += 64) out[(size_t)wb0 * 18 + i] = S[i];
    }
}

extern "C" void kernel_launch(void* const* d_in, const int* in_sizes, int n_in,
                              void* d_out, int out_size, void* d_ws, size_t ws_size,
                              hipStream_t stream) {
    const float* U0_re = (const float*)d_in[0];
    const float* U0_im = (const float*)d_in[1];
    const float* xs    = (const float*)d_in[2];
    const float* V_re  = (const float*)d_in[3];
    const float* V_im  = (const float*)d_in[4];
    float* out = (float*)d_out;

    const int nb = in_sizes[2] / 3;
    const int grid = (nb + BPB - 1) / BPB;
    sun_diffuse_kernel<<<grid, 256, 0, stream>>>(U0_re, U0_im, xs, V_re, V_im, out, nb);
}